// Round 1
// baseline (546.971 us; speedup 1.0000x reference)
//
#include <hip/hip_runtime.h>
#include <hip/hip_bf16.h>
#include <stdint.h>

#define NB 64
#define NV 2048
#define NL 512
#define DK 512
#define BM 256
#define BN 256
#define BK 64
#define NT (DK / BK)   // 8 K-tiles

typedef __attribute__((ext_vector_type(8))) short bf16x8;
typedef __attribute__((ext_vector_type(4))) float f32x4;

// order-preserving float -> uint map (for atomicMin); all-ones = +infinity sentinel
__device__ __forceinline__ unsigned enc_f(float f) {
  unsigned u = __float_as_uint(f);
  return (u & 0x80000000u) ? ~u : (u | 0x80000000u);
}
__device__ __forceinline__ float dec_f(unsigned u) {
  unsigned b = (u & 0x80000000u) ? (u ^ 0x80000000u) : ~u;
  return __uint_as_float(b);
}

// fp32 -> bf16 (RNE); inputs finite, no NaN path
__device__ __forceinline__ unsigned short f2bf(float f) {
  unsigned u = __float_as_uint(f);
  u += 0x7FFFu + ((u >> 16) & 1u);
  return (unsigned short)(u >> 16);
}
__device__ __forceinline__ unsigned pack_bf2(float lo, float hi) {
  return (unsigned)f2bf(lo) | ((unsigned)f2bf(hi) << 16);
}

// async global->LDS, 16 B per lane; LDS dest = wave-uniform base + lane*16
__device__ __forceinline__ void gload_lds16(const void* g, void* l) {
  __builtin_amdgcn_global_load_lds(
      (const __attribute__((address_space(1))) unsigned*)g,
      (__attribute__((address_space(3))) unsigned*)l, 16, 0, 0);
}

// ---------------- Pass 1: fp32 -> bf16 + exact fp32 row norms + min-sentinel init -------
// one wave per row of 512 floats; lane handles 8 consecutive elems -> one 16B store.
__global__ __launch_bounds__(256) void convert_norm(
    const float* __restrict__ video, const float* __restrict__ lang,
    unsigned short* __restrict__ Vb, unsigned short* __restrict__ Lb,
    float* __restrict__ vnorm, float* __restrict__ lnorm,
    unsigned* __restrict__ rowmin, unsigned* __restrict__ colmin) {
  const int t = threadIdx.x;
  const int lane = t & 63;
  const int row = blockIdx.x * 4 + (t >> 6);
  const int rows_v = NB * NV;

  const float* src;
  unsigned short* dst;
  float* nrm;
  unsigned* sent;
  size_t r;
  if (row < rows_v) { src = video; dst = Vb; nrm = vnorm; sent = rowmin; r = (size_t)row; }
  else              { src = lang;  dst = Lb;  nrm = lnorm; sent = colmin; r = (size_t)(row - rows_v); }

  const float4* p = (const float4*)(src + r * DK);
  const float4 a = p[lane * 2];
  const float4 b = p[lane * 2 + 1];

  float n = a.x * a.x + a.y * a.y + a.z * a.z + a.w * a.w
          + b.x * b.x + b.y * b.y + b.z * b.z + b.w * b.w;
  #pragma unroll
  for (int m = 1; m < 64; m <<= 1) n += __shfl_xor(n, m, 64);

  uint4 pk;
  pk.x = pack_bf2(a.x, a.y); pk.y = pack_bf2(a.z, a.w);
  pk.z = pack_bf2(b.x, b.y); pk.w = pack_bf2(b.z, b.w);
  ((uint4*)(dst + r * DK))[lane] = pk;
  if (lane == 0) {
    nrm[r] = n;
    sent[r] = 0xFFFFFFFFu;   // +inf sentinel for atomicMin
  }
}

// ---------------- Pass 2: 256x256-tile bf16 GEMM + chamfer mins -----------------------
// 8 waves (2M x 4N), per-wave 128x64 output = acc[8][4] 16x16 frags. BK=64 K-tiles,
// split in two k-halves of 32. LDS [buf][kh][256][32] bf16: row stride 64 B makes
// ds_read_b128 frag reads bank-quad-uniform (no swizzle needed, conflict-free).
// Pipeline: prefetch 1 K-tile ahead as 4 half-tiles (A-k0,B-k0,A-k1,B-k1), one issued
// per phase; s_waitcnt vmcnt(4) + raw s_barrier at the two consume points keeps 4
// loads in flight across barriers (counted vmcnt, never 0 in loop).
// Write-after-read safety: a region's ds_reads are consumed by MFMAs (lgkm drain)
// before the wave reaches the barrier that precedes the overwriting gload issue.

template <int C>
__device__ __forceinline__ void ktile(
    int t, int w, int wm, int wn, int c16, int hi,
    const unsigned short* As, const unsigned short* Bs,
    unsigned short (*Asm)[2][BM][32], unsigned short (*Bsm)[2][BN][32],
    f32x4 (&acc)[8][4]) {
  constexpr int N_ = C ^ 1;
  const int tn = (t < NT - 1) ? t + 1 : t;   // last tile re-prefetches itself (harmless)
  const int ko = tn * BK;

  // ---- W1: A-k0/B-k0 of tile t resident after this (4 newest loads stay in flight)
  asm volatile("s_waitcnt vmcnt(4)" ::: "memory");
  __builtin_amdgcn_s_barrier();

  bf16x8 bf[4], af[4];
  // p0: stage A-k0(tn) -> buf N_; compute kh=0, i 0..3
  gload_lds16(As + ko,           &Asm[N_][0][w * 32][0]);
  gload_lds16(As + 16 * DK + ko, &Asm[N_][0][w * 32 + 16][0]);
  #pragma unroll
  for (int j = 0; j < 4; ++j)
    bf[j] = *(const bf16x8*)&Bsm[C][0][wn * 64 + j * 16 + c16][hi * 8];
  #pragma unroll
  for (int i = 0; i < 4; ++i)
    af[i] = *(const bf16x8*)&Asm[C][0][wm * 128 + i * 16 + c16][hi * 8];
  __builtin_amdgcn_s_setprio(1);
  #pragma unroll
  for (int i = 0; i < 4; ++i)
    #pragma unroll
    for (int j = 0; j < 4; ++j)
      acc[i][j] = __builtin_amdgcn_mfma_f32_16x16x32_bf16(af[i], bf[j], acc[i][j], 0, 0, 0);
  __builtin_amdgcn_s_setprio(0);

  // p1: stage B-k0(tn); compute kh=0, i 4..7
  gload_lds16(Bs + ko,           &Bsm[N_][0][w * 32][0]);
  gload_lds16(Bs + 16 * DK + ko, &Bsm[N_][0][w * 32 + 16][0]);
  #pragma unroll
  for (int i = 0; i < 4; ++i)
    af[i] = *(const bf16x8*)&Asm[C][0][wm * 128 + 64 + i * 16 + c16][hi * 8];
  __builtin_amdgcn_s_setprio(1);
  #pragma unroll
  for (int i = 0; i < 4; ++i)
    #pragma unroll
    for (int j = 0; j < 4; ++j)
      acc[i + 4][j] = __builtin_amdgcn_mfma_f32_16x16x32_bf16(af[i], bf[j], acc[i + 4][j], 0, 0, 0);
  __builtin_amdgcn_s_setprio(0);

  // ---- W2: A-k1/B-k1 of tile t resident after this
  asm volatile("s_waitcnt vmcnt(4)" ::: "memory");
  __builtin_amdgcn_s_barrier();

  // p2: stage A-k1(tn); compute kh=1, i 0..3
  gload_lds16(As + ko + 32,           &Asm[N_][1][w * 32][0]);
  gload_lds16(As + 16 * DK + ko + 32, &Asm[N_][1][w * 32 + 16][0]);
  #pragma unroll
  for (int j = 0; j < 4; ++j)
    bf[j] = *(const bf16x8*)&Bsm[C][1][wn * 64 + j * 16 + c16][hi * 8];
  #pragma unroll
  for (int i = 0; i < 4; ++i)
    af[i] = *(const bf16x8*)&Asm[C][1][wm * 128 + i * 16 + c16][hi * 8];
  __builtin_amdgcn_s_setprio(1);
  #pragma unroll
  for (int i = 0; i < 4; ++i)
    #pragma unroll
    for (int j = 0; j < 4; ++j)
      acc[i][j] = __builtin_amdgcn_mfma_f32_16x16x32_bf16(af[i], bf[j], acc[i][j], 0, 0, 0);
  __builtin_amdgcn_s_setprio(0);

  // p3: stage B-k1(tn); compute kh=1, i 4..7
  gload_lds16(Bs + ko + 32,           &Bsm[N_][1][w * 32][0]);
  gload_lds16(Bs + 16 * DK + ko + 32, &Bsm[N_][1][w * 32 + 16][0]);
  #pragma unroll
  for (int i = 0; i < 4; ++i)
    af[i] = *(const bf16x8*)&Asm[C][1][wm * 128 + 64 + i * 16 + c16][hi * 8];
  __builtin_amdgcn_s_setprio(1);
  #pragma unroll
  for (int i = 0; i < 4; ++i)
    #pragma unroll
    for (int j = 0; j < 4; ++j)
      acc[i + 4][j] = __builtin_amdgcn_mfma_f32_16x16x32_bf16(af[i], bf[j], acc[i + 4][j], 0, 0, 0);
  __builtin_amdgcn_s_setprio(0);
}

__global__ __launch_bounds__(512, 2) void chamfer_gemm(
    const unsigned short* __restrict__ Vb, const unsigned short* __restrict__ Lb,
    const float* __restrict__ vnorm, const float* __restrict__ lnorm,
    unsigned* __restrict__ rowmin, unsigned* __restrict__ colmin) {
  __shared__ unsigned short Asm[2][2][BM][32];   // 64 KiB
  __shared__ unsigned short Bsm[2][2][BN][32];   // 64 KiB

  // bijective XCD swizzle: 1024 wgs, 128 contiguous logical wgs (= 8 batches) per XCD
  const int bid0 = blockIdx.x;
  const int bid = (bid0 & 7) * 128 + (bid0 >> 3);
  const int b  = bid >> 4;
  const int vt = (bid >> 1) & 7;
  const int lt = bid & 1;

  const unsigned short* Ag = Vb + ((size_t)b * NV + (size_t)vt * BM) * DK;
  const unsigned short* Bg = Lb + ((size_t)b * NL + (size_t)lt * BN) * DK;

  const int t = threadIdx.x;
  const int lane = t & 63;
  const int w = t >> 6;        // wave 0..7
  const int wm = w >> 2;       // 0..1  (row block of 128)
  const int wn = w & 3;        // 0..3  (col block of 64)
  const int c16 = lane & 15;
  const int hi  = lane >> 4;

  // staging: wave w stages rows w*32 .. w*32+31 of each half-tile.
  // issue covers 16 rows (64 lanes x 16 B over 64 B rows): row = base + lane/4,
  // chunk = lane%4 -> source element offset (lane%4)*8 within the 32-wide k-half.
  const int srow = w * 32 + (lane >> 2);
  const unsigned short* As = Ag + (size_t)srow * DK + (lane & 3) * 8;
  const unsigned short* Bs = Bg + (size_t)srow * DK + (lane & 3) * 8;

  f32x4 acc[8][4];
  #pragma unroll
  for (int i = 0; i < 8; ++i)
    #pragma unroll
    for (int j = 0; j < 4; ++j)
      acc[i][j] = (f32x4){0.f, 0.f, 0.f, 0.f};

  // prologue: stage all 4 halves of tile 0 into buf 0, order A0 B0 A1 B1
  // (order must match the in-loop issue stream so vmcnt(4) drains the right halves)
  gload_lds16(As,                &Asm[0][0][w * 32][0]);
  gload_lds16(As + 16 * DK,      &Asm[0][0][w * 32 + 16][0]);
  gload_lds16(Bs,                &Bsm[0][0][w * 32][0]);
  gload_lds16(Bs + 16 * DK,      &Bsm[0][0][w * 32 + 16][0]);
  gload_lds16(As + 32,           &Asm[0][1][w * 32][0]);
  gload_lds16(As + 16 * DK + 32, &Asm[0][1][w * 32 + 16][0]);
  gload_lds16(Bs + 32,           &Bsm[0][1][w * 32][0]);
  gload_lds16(Bs + 16 * DK + 32, &Bsm[0][1][w * 32 + 16][0]);

  #pragma unroll
  for (int t2 = 0; t2 < NT; t2 += 2) {
    ktile<0>(t2,     w, wm, wn, c16, hi, As, Bs, Asm, Bsm, acc);
    ktile<1>(t2 + 1, w, wm, wn, c16, hi, As, Bs, Asm, Bsm, acc);
  }

  // drain tail prefetches before LDS goes away / epilogue
  asm volatile("s_waitcnt vmcnt(0)" ::: "memory");
  __builtin_amdgcn_s_barrier();

  // epilogue: P = rn + cn - 2*dot; C layout col=lane&15, row=(lane>>4)*4+reg
  const size_t rowbase = (size_t)b * NV + (size_t)vt * BM + (size_t)wm * 128;
  const size_t colbase = (size_t)b * NL + (size_t)lt * BN + (size_t)wn * 64;

  float cn[4];
  #pragma unroll
  for (int j = 0; j < 4; ++j) cn[j] = lnorm[colbase + j * 16 + c16];

  float cmin[4];
  #pragma unroll
  for (int j = 0; j < 4; ++j) cmin[j] = 3.0e38f;

  #pragma unroll
  for (int i = 0; i < 8; ++i) {
    #pragma unroll
    for (int r = 0; r < 4; ++r) {
      const float rn = vnorm[rowbase + i * 16 + hi * 4 + r];
      float m = 3.0e38f;
      #pragma unroll
      for (int j = 0; j < 4; ++j) {
        const float P = rn + cn[j] - 2.0f * acc[i][j][r];
        m = fminf(m, P);
        cmin[j] = fminf(cmin[j], P);
      }
      #pragma unroll
      for (int mm = 1; mm < 16; mm <<= 1)
        m = fminf(m, __shfl_xor(m, mm, 64));
      if (c16 == 0)
        atomicMin(&rowmin[rowbase + i * 16 + hi * 4 + r], enc_f(m));
    }
  }
  #pragma unroll
  for (int j = 0; j < 4; ++j) {
    float m = cmin[j];
    m = fminf(m, __shfl_xor(m, 16, 64));
    m = fminf(m, __shfl_xor(m, 32, 64));
    if (hi == 0)
      atomicMin(&colmin[colbase + j * 16 + c16], enc_f(m));
  }
}

__global__ void chamfer_reduce(const unsigned* __restrict__ rowmin,
                               const unsigned* __restrict__ colmin,
                               float* __restrict__ out) {
  const int b = blockIdx.x;
  const int t = threadIdx.x;
  float s = 0.f;
  for (int i = t; i < NV; i += 256) s += dec_f(rowmin[(size_t)b * NV + i]) * (1.0f / NV);
  for (int i = t; i < NL; i += 256) s += dec_f(colmin[(size_t)b * NL + i]) * (1.0f / NL);
  #pragma unroll
  for (int m = 1; m < 64; m <<= 1) s += __shfl_xor(s, m, 64);
  __shared__ float ws[4];
  if ((t & 63) == 0) ws[t >> 6] = s;
  __syncthreads();
  if (t == 0) out[b] = ws[0] + ws[1] + ws[2] + ws[3];
}

extern "C" void kernel_launch(void* const* d_in, const int* in_sizes, int n_in,
                              void* d_out, int out_size, void* d_ws, size_t ws_size,
                              hipStream_t stream) {
  const float* video = (const float*)d_in[0];
  const float* lang  = (const float*)d_in[1];
  float* out = (float*)d_out;

  const size_t vb_elems = (size_t)NB * NV * DK;   // 67.1M bf16
  const size_t lb_elems = (size_t)NB * NL * DK;   // 16.8M bf16

  unsigned short* Vb = (unsigned short*)d_ws;
  unsigned short* Lb = Vb + vb_elems;
  float* vnorm = (float*)(Lb + lb_elems);
  float* lnorm = vnorm + (size_t)NB * NV;
  unsigned* rowmin = (unsigned*)(lnorm + (size_t)NB * NL);
  unsigned* colmin = rowmin + (size_t)NB * NV;

  convert_norm<<<dim3((NB * NV + NB * NL) / 4), dim3(256), 0, stream>>>(
      video, lang, Vb, Lb, vnorm, lnorm, rowmin, colmin);
  chamfer_gemm<<<dim3(NB * 16), dim3(512), 0, stream>>>(
      Vb, Lb, vnorm, lnorm, rowmin, colmin);
  chamfer_reduce<<<dim3(NB), dim3(256), 0, stream>>>(rowmin, colmin, out);
}